// Round 1
// baseline (469.909 us; speedup 1.0000x reference)
//
#include <hip/hip_runtime.h>

// 23-tap halfband filter: nonzero at center (1.0) and odd offsets only.
__device__ constexpr float TAPS[23] = {
    -1.20162964e-04f, 0.0f,  1.615524292e-03f, 0.0f, -1.0385513306e-02f, 0.0f,
     4.3619155884e-02f, 0.0f, -1.45397186478e-01f, 0.0f,  6.1066818237e-01f,
     1.0f,
     6.1066818237e-01f, 0.0f, -1.45397186478e-01f, 0.0f,  4.3619155884e-02f, 0.0f,
    -1.0385513306e-02f, 0.0f,  1.615524292e-03f, 0.0f, -1.20162964e-04f
};

// Geometry: BC = 16*8 = 128 slices. Stage1: 160 -> 320 (off=1). Stage2: 320 -> 640 (off=0).

// K1: stage-1 width pass. Reads x[bc][160][160], writes mid[bc][2*ri+1][c2] (odd rows).
// up (320 wide) has data at odd columns j (off=1): up[j] = x[(j-1)/2]; edge-pad = clamp.
__global__ __launch_bounds__(256) void k_width1(const float* __restrict__ x,
                                                float* __restrict__ mid) {
    int idx = blockIdx.x * blockDim.x + threadIdx.x;           // 128*160*320
    int c2 = idx % 320;
    int t1 = idx / 320;
    int ri = t1 % 160;
    int bc = t1 / 160;
    const float* xr = x + (bc * 160 + ri) * 160;
    float acc = 0.f;
#pragma unroll
    for (int t = 0; t < 23; ++t) {
        int j = c2 - 11 + t;
        j = j < 0 ? 0 : (j > 319 ? 319 : j);
        if (j & 1) acc += TAPS[t] * xr[(j - 1) >> 1];          // off=1: odd j carry data
    }
    mid[(bc * 320 + (2 * ri + 1)) * 320 + c2] = acc;
}

// K2: stage-1 height pass, in-place on mid. Writes even rows r2=2k, reads odd rows only
// (wrap pad). r = r2-11+t is odd iff t even; even-t taps are the 12 nonzero odd-offset taps.
__global__ __launch_bounds__(256) void k_height1(float* __restrict__ mid) {
    int idx = blockIdx.x * blockDim.x + threadIdx.x;           // 128*160*80
    int c4 = idx % 80;
    int t1 = idx / 80;
    int k  = t1 % 160;
    int bc = t1 / 160;
    int r2 = 2 * k;
    float* base = mid + (size_t)bc * 320 * 320;
    float ax = 0.f, ay = 0.f, az = 0.f, aw = 0.f;
#pragma unroll
    for (int t = 0; t < 23; t += 2) {
        int r = r2 - 11 + t;
        r = r < 0 ? r + 320 : (r >= 320 ? r - 320 : r);
        const float4 v = *(const float4*)(base + r * 320 + 4 * c4);
        const float w = TAPS[t];
        ax += w * v.x; ay += w * v.y; az += w * v.z; aw += w * v.w;
    }
    float4 o; o.x = ax; o.y = ay; o.z = az; o.w = aw;
    *(float4*)(base + r2 * 320 + 4 * c4) = o;
}

// K3: stage-2 width pass. Reads full mid[bc][320][320], writes out even rows (r2=2*ri).
// up2 (640 wide) has data at even columns j (off=0): up2[j] = mid[j/2]; edge-pad = clamp.
__global__ __launch_bounds__(256) void k_width2(const float* __restrict__ mid,
                                                float* __restrict__ out) {
    int idx = blockIdx.x * blockDim.x + threadIdx.x;           // 128*320*640
    int c2 = idx % 640;
    int t1 = idx / 640;
    int ri = t1 % 320;
    int bc = t1 / 320;
    const float* mr = mid + ((size_t)bc * 320 + ri) * 320;
    float acc = 0.f;
#pragma unroll
    for (int t = 0; t < 23; ++t) {
        int j = c2 - 11 + t;
        j = j < 0 ? 0 : (j > 639 ? 639 : j);
        if (!(j & 1)) acc += TAPS[t] * mr[j >> 1];             // off=0: even j carry data
    }
    out[((size_t)bc * 640 + 2 * ri) * 640 + c2] = acc;
}

// K4: stage-2 height pass, in-place on out. Writes odd rows r2=2k+1, reads even rows only
// (wrap pad). r2 odd => r = r2-11+t even iff t even; same 12 nonzero taps.
__global__ __launch_bounds__(256) void k_height2(float* __restrict__ out) {
    int idx = blockIdx.x * blockDim.x + threadIdx.x;           // 128*320*160
    int c4 = idx % 160;
    int t1 = idx / 160;
    int k  = t1 % 320;
    int bc = t1 / 320;
    int r2 = 2 * k + 1;
    float* base = out + (size_t)bc * 640 * 640;
    float ax = 0.f, ay = 0.f, az = 0.f, aw = 0.f;
#pragma unroll
    for (int t = 0; t < 23; t += 2) {
        int r = r2 - 11 + t;
        r = r < 0 ? r + 640 : (r >= 640 ? r - 640 : r);
        const float4 v = *(const float4*)(base + r * 640 + 4 * c4);
        const float w = TAPS[t];
        ax += w * v.x; ay += w * v.y; az += w * v.z; aw += w * v.w;
    }
    float4 o; o.x = ax; o.y = ay; o.z = az; o.w = aw;
    *(float4*)(base + r2 * 640 + 4 * c4) = o;
}

extern "C" void kernel_launch(void* const* d_in, const int* in_sizes, int n_in,
                              void* d_out, int out_size, void* d_ws, size_t ws_size,
                              hipStream_t stream) {
    const float* x = (const float*)d_in[0];
    float* out = (float*)d_out;
    float* mid = (float*)d_ws;  // 128*320*320 floats = 52.4 MB

    // K1: 128*160*320 = 6,553,600 threads
    k_width1 <<<25600, 256, 0, stream>>>(x, mid);
    // K2: 128*160*80 = 1,638,400 threads (float4)
    k_height1<<<6400, 256, 0, stream>>>(mid);
    // K3: 128*320*640 = 26,214,400 threads
    k_width2 <<<102400, 256, 0, stream>>>(mid, out);
    // K4: 128*320*160 = 6,553,600 threads (float4)
    k_height2<<<25600, 256, 0, stream>>>(out);
}

// Round 3
// 226.278 us; speedup vs baseline: 2.0767x; 2.0767x over previous
//
#include <hip/hip_runtime.h>

// The 12 nonzero taps of the 23-tap halfband filter (even indices 0,2,..,22).
// The only other nonzero tap is the center (index 11) with weight 1.0 -> pure copy.
__device__ constexpr float W12[12] = {
    -1.20162964e-04f,    1.615524292e-03f, -1.0385513306e-02f,  4.3619155884e-02f,
    -1.45397186478e-01f, 6.1066818237e-01f, 6.1066818237e-01f, -1.45397186478e-01f,
     4.3619155884e-02f, -1.0385513306e-02f, 1.615524292e-03f,  -1.20162964e-04f
};

// Geometry: BC = 16*8 = 128 slices. Stage1: 160->320 (off=1). Stage2: 320->640 (off=0).

// K1: stage-1 width pass. Reads x[bc][160][160], writes mid odd rows (2*ri+1).
// off=1: data at odd up-cols. Odd out col 2i+1 = x[i] + right-edge correction;
// even out col 2i = sum_s W12[s]*x[i-6+s] with (left->0, right->x[159]) pad.
// Right-edge correction (clamp flips parity): + sum_{s: i+s>=165} W12[s] * x[159].
__global__ __launch_bounds__(256) void k_width1(const float* __restrict__ x,
                                                float* __restrict__ mid) {
    int idx = blockIdx.x * blockDim.x + threadIdx.x;   // 128*160*40
    int q  = idx % 40;
    int t1 = idx / 40;
    int ri = t1 % 160;
    int bc = t1 / 160;
    int i0 = 4 * q;
    const float* xr = x + (bc * 160 + ri) * 160;
    float m[15];
#pragma unroll
    for (int e = 0; e < 15; ++e) {
        int g = i0 - 6 + e;
        int gc = g < 159 ? g : 159;
        float v = xr[gc < 0 ? 0 : gc];
        m[e] = (g < 0) ? 0.f : v;
    }
    float f[4], cpy[4];
#pragma unroll
    for (int d = 0; d < 4; ++d) {
        float acc = 0.f;
#pragma unroll
        for (int s = 0; s < 12; ++s) acc += W12[s] * m[d + s];
        f[d] = acc;
        cpy[d] = m[d + 6];
    }
    if (i0 >= 151) {                      // only q=38,39 can need the correction
        float x159 = xr[159];
#pragma unroll
        for (int d = 0; d < 4; ++d) {
            int i = i0 + d;
            float c = 0.f;
#pragma unroll
            for (int s = 0; s < 12; ++s) if (i + s >= 165) c += W12[s];
            cpy[d] += c * x159;
        }
    }
    float4 o0, o1;
    o0.x = f[0]; o0.y = cpy[0]; o0.z = f[1]; o0.w = cpy[1];
    o1.x = f[2]; o1.y = cpy[2]; o1.z = f[3]; o1.w = cpy[3];
    float* orow = mid + ((size_t)bc * 320 + (2 * ri + 1)) * 320 + 8 * q;
    *(float4*)(orow)     = o0;
    *(float4*)(orow + 4) = o1;
}

// K2: stage-1 height pass, in-place on mid. Writes even rows r2=2k from the 12
// nonzero taps reading odd rows r2-11+2s (wrap pad; 320 even -> parity preserved).
__global__ __launch_bounds__(256) void k_height1(float* __restrict__ mid) {
    int idx = blockIdx.x * blockDim.x + threadIdx.x;   // 128*160*80
    int c4 = idx % 80;
    int t1 = idx / 80;
    int k  = t1 % 160;
    int bc = t1 / 160;
    int r2 = 2 * k;
    float* base = mid + (size_t)bc * 320 * 320;
    float ax = 0.f, ay = 0.f, az = 0.f, aw = 0.f;
#pragma unroll
    for (int s = 0; s < 12; ++s) {
        int r = r2 - 11 + 2 * s;
        r = r < 0 ? r + 320 : (r >= 320 ? r - 320 : r);
        const float4 v = *(const float4*)(base + r * 320 + 4 * c4);
        const float w = W12[s];
        ax += w * v.x; ay += w * v.y; az += w * v.z; aw += w * v.w;
    }
    float4 o; o.x = ax; o.y = ay; o.z = az; o.w = aw;
    *(float4*)(base + r2 * 320 + 4 * c4) = o;
}

// K3: stage-2 width pass. Reads mid[bc][320][320], writes out even rows (2*ri).
// off=0: data at even up2-cols. Even out col 2i = mid[i] + left-edge correction;
// odd out col 2i+1 = sum_s W12[s]*mid[i-5+s] with (left->mid[0], right->0) pad.
// Left-edge correction (clamp flips parity): + sum_{s: i+s<=5} W12[s] * mid[0].
__global__ __launch_bounds__(256) void k_width2(const float* __restrict__ mid,
                                                float* __restrict__ out) {
    int idx = blockIdx.x * blockDim.x + threadIdx.x;   // 128*320*80
    int q  = idx % 80;
    int t1 = idx / 80;
    int ri = t1 % 320;
    int bc = t1 / 320;
    int i0 = 4 * q;
    const float* mr = mid + ((size_t)bc * 320 + ri) * 320;
    float m[15];
#pragma unroll
    for (int e = 0; e < 15; ++e) {
        int g = i0 - 5 + e;
        int gc = g < 0 ? 0 : g;
        float v = mr[gc < 319 ? gc : 319];
        m[e] = (g > 319) ? 0.f : v;
    }
    float f[4], cpy[4];
#pragma unroll
    for (int d = 0; d < 4; ++d) {
        float acc = 0.f;
#pragma unroll
        for (int s = 0; s < 12; ++s) acc += W12[s] * m[d + s];
        f[d] = acc;
        cpy[d] = m[d + 5];
    }
    if (i0 <= 5) {                        // only q=0,1 can need the correction
        float m0 = mr[0];
#pragma unroll
        for (int d = 0; d < 4; ++d) {
            int i = i0 + d;
            float c = 0.f;
#pragma unroll
            for (int s = 0; s < 12; ++s) if (i + s <= 5) c += W12[s];
            cpy[d] += c * m0;
        }
    }
    float4 o0, o1;
    o0.x = cpy[0]; o0.y = f[0]; o0.z = cpy[1]; o0.w = f[1];
    o1.x = cpy[2]; o1.y = f[2]; o1.z = cpy[3]; o1.w = f[3];
    float* orow = out + ((size_t)bc * 640 + 2 * ri) * 640 + 8 * q;
    *(float4*)(orow)     = o0;
    *(float4*)(orow + 4) = o1;
}

// K4: stage-2 height pass, in-place on out. Writes odd rows r2=2k+1 from the 12
// nonzero taps reading even rows r2-11+2s (wrap pad; 640 even -> parity preserved).
__global__ __launch_bounds__(256) void k_height2(float* __restrict__ out) {
    int idx = blockIdx.x * blockDim.x + threadIdx.x;   // 128*320*160
    int c4 = idx % 160;
    int t1 = idx / 160;
    int k  = t1 % 320;
    int bc = t1 / 320;
    int r2 = 2 * k + 1;
    float* base = out + (size_t)bc * 640 * 640;
    float ax = 0.f, ay = 0.f, az = 0.f, aw = 0.f;
#pragma unroll
    for (int s = 0; s < 12; ++s) {
        int r = r2 - 11 + 2 * s;
        r = r < 0 ? r + 640 : (r >= 640 ? r - 640 : r);
        const float4 v = *(const float4*)(base + r * 640 + 4 * c4);
        const float w = W12[s];
        ax += w * v.x; ay += w * v.y; az += w * v.z; aw += w * v.w;
    }
    float4 o; o.x = ax; o.y = ay; o.z = az; o.w = aw;
    *(float4*)(base + r2 * 640 + 4 * c4) = o;
}

extern "C" void kernel_launch(void* const* d_in, const int* in_sizes, int n_in,
                              void* d_out, int out_size, void* d_ws, size_t ws_size,
                              hipStream_t stream) {
    const float* x = (const float*)d_in[0];
    float* out = (float*)d_out;
    float* mid = (float*)d_ws;  // 128*320*320 floats = 52.4 MB

    // K1: 128*160*40 = 819,200 threads
    k_width1 <<<3200, 256, 0, stream>>>(x, mid);
    // K2: 128*160*80 = 1,638,400 threads (float4)
    k_height1<<<6400, 256, 0, stream>>>(mid);
    // K3: 128*320*80 = 3,276,800 threads
    k_width2 <<<12800, 256, 0, stream>>>(mid, out);
    // K4: 128*320*160 = 6,553,600 threads (float4)
    k_height2<<<25600, 256, 0, stream>>>(out);
}

// Round 4
// 141.863 us; speedup vs baseline: 3.3124x; 1.5950x over previous
//
#include <hip/hip_runtime.h>

// The 12 nonzero taps of the 23-tap halfband filter (even indices 0,2,..,22).
// The only other nonzero tap is the center (index 11) with weight 1.0 -> pure copy.
__device__ constexpr float W12[12] = {
    -1.20162964e-04f,    1.615524292e-03f, -1.0385513306e-02f,  4.3619155884e-02f,
    -1.45397186478e-01f, 6.1066818237e-01f, 6.1066818237e-01f, -1.45397186478e-01f,
     4.3619155884e-02f, -1.0385513306e-02f, 1.615524292e-03f,  -1.20162964e-04f
};

// Bijective XCD-chunking swizzle (grid % 8 == 0): dispatched block bid runs on
// XCD bid%8; give that XCD the contiguous work chunk so row-stencil rereads hit L2.
__device__ __forceinline__ int xcd_map(int bid, int nblk) {
    int cpx = nblk >> 3;
    return (bid & 7) * cpx + (bid >> 3);
}

// Geometry: BC = 16*8 = 128 slices. Stage1: 160->320 (off=1). Stage2: 320->640 (off=0).

// K1: stage-1 width pass. Reads x[bc][160][160], writes mid odd rows (2*ri+1).
// off=1: odd out col 2i+1 = x[i] (+right-edge corr); even out col 2i = 12-tap on x.
// Window loads: 5 clamped-block float4 + branchless edge patches (no divergent scalar path).
__global__ __launch_bounds__(256) void k_width1(const float* __restrict__ x,
                                                float* __restrict__ mid) {
    int idx = blockIdx.x * blockDim.x + threadIdx.x;   // 128*160*40
    int q  = idx % 40;
    int t1 = idx / 40;
    int ri = t1 % 160;
    int bc = t1 / 160;
    int i0 = 4 * q;
    const float* xr = x + (bc * 160 + ri) * 160;
    float flat[20];
#pragma unroll
    for (int b = 0; b < 5; ++b) {
        int bq = q - 2 + b; bq = bq < 0 ? 0 : (bq > 39 ? 39 : bq);
        *(float4*)(flat + 4 * b) = *(const float4*)(xr + 4 * bq);
    }
    // m[e] = up-window; in-range g=i0-6+e sits at flat[e+2] with unclamped block.
    float m[15];
#pragma unroll
    for (int e = 0; e < 15; ++e) m[e] = flat[e + 2];
#pragma unroll
    for (int e = 0; e < 6; ++e)  m[e] = (i0 - 6 + e < 0) ? 0.f : m[e];     // left pad -> 0
    float xlast = flat[19];  // = xr[159] whenever any g>159 (q>=38 clamps top block to 39)
#pragma unroll
    for (int e = 10; e < 15; ++e) m[e] = (i0 - 6 + e > 159) ? xlast : m[e]; // right pad -> x[159]

    float f[4], cpy[4];
#pragma unroll
    for (int d = 0; d < 4; ++d) {
        float acc = 0.f;
#pragma unroll
        for (int s = 0; s < 12; ++s) acc += W12[s] * m[d + s];
        f[d] = acc;
        cpy[d] = m[d + 6];
    }
    if (i0 >= 151) {                      // right-edge copy correction (q=38,39 only)
#pragma unroll
        for (int d = 0; d < 4; ++d) {
            int i = i0 + d;
            float c = 0.f;
#pragma unroll
            for (int s = 0; s < 12; ++s) if (i + s >= 165) c += W12[s];
            cpy[d] += c * xlast;
        }
    }
    float4 o0, o1;
    o0.x = f[0]; o0.y = cpy[0]; o0.z = f[1]; o0.w = cpy[1];
    o1.x = f[2]; o1.y = cpy[2]; o1.z = f[3]; o1.w = cpy[3];
    float* orow = mid + ((size_t)bc * 320 + (2 * ri + 1)) * 320 + 8 * q;
    *(float4*)(orow)     = o0;
    *(float4*)(orow + 4) = o1;
}

// K2: stage-1 height pass, in-place on mid. Writes even rows r2=2k from the 12
// nonzero taps reading odd rows r2-11+2s (wrap pad; 320 even -> parity preserved).
__global__ __launch_bounds__(256) void k_height1(float* __restrict__ mid) {
    int idx = xcd_map(blockIdx.x, gridDim.x) * blockDim.x + threadIdx.x;   // 128*160*80
    int c4 = idx % 80;
    int t1 = idx / 80;
    int k  = t1 % 160;
    int bc = t1 / 160;
    int r2 = 2 * k;
    float* base = mid + (size_t)bc * 320 * 320;
    float ax = 0.f, ay = 0.f, az = 0.f, aw = 0.f;
#pragma unroll
    for (int s = 0; s < 12; ++s) {
        int r = r2 - 11 + 2 * s;
        r = r < 0 ? r + 320 : (r >= 320 ? r - 320 : r);
        const float4 v = *(const float4*)(base + r * 320 + 4 * c4);
        const float w = W12[s];
        ax += w * v.x; ay += w * v.y; az += w * v.z; aw += w * v.w;
    }
    float4 o; o.x = ax; o.y = ay; o.z = az; o.w = aw;
    *(float4*)(base + r2 * 320 + 4 * c4) = o;
}

// K3: stage-2 width pass. Reads mid[bc][320][320], writes out even rows (2*ri).
// off=0: even out col 2i = mid[i] (+left-edge corr); odd out col 2i+1 = 12-tap on mid.
__global__ __launch_bounds__(256) void k_width2(const float* __restrict__ mid,
                                                float* __restrict__ out) {
    int idx = blockIdx.x * blockDim.x + threadIdx.x;   // 128*320*80
    int q  = idx % 80;
    int t1 = idx / 80;
    int ri = t1 % 320;
    int bc = t1 / 320;
    int i0 = 4 * q;
    const float* mr = mid + ((size_t)bc * 320 + ri) * 320;
    float flat[20];
#pragma unroll
    for (int b = 0; b < 5; ++b) {
        int bq = q - 2 + b; bq = bq < 0 ? 0 : (bq > 79 ? 79 : bq);
        *(float4*)(flat + 4 * b) = *(const float4*)(mr + 4 * bq);
    }
    // in-range g=i0-5+e sits at flat[e+3] with unclamped block.
    float m[15];
#pragma unroll
    for (int e = 0; e < 15; ++e) m[e] = flat[e + 3];
    float m0 = flat[0];  // = mr[0] whenever any g<0 (q<=2 clamps bottom block to 0)
#pragma unroll
    for (int e = 0; e < 5; ++e)  m[e] = (i0 - 5 + e < 0) ? m0 : m[e];       // left pad -> mid[0]
#pragma unroll
    for (int e = 9; e < 15; ++e) m[e] = (i0 - 5 + e > 319) ? 0.f : m[e];    // right pad -> 0

    float f[4], cpy[4];
#pragma unroll
    for (int d = 0; d < 4; ++d) {
        float acc = 0.f;
#pragma unroll
        for (int s = 0; s < 12; ++s) acc += W12[s] * m[d + s];
        f[d] = acc;
        cpy[d] = m[d + 5];
    }
    if (i0 <= 5) {                        // left-edge copy correction (q=0,1 only)
#pragma unroll
        for (int d = 0; d < 4; ++d) {
            int i = i0 + d;
            float c = 0.f;
#pragma unroll
            for (int s = 0; s < 12; ++s) if (i + s <= 5) c += W12[s];
            cpy[d] += c * m0;
        }
    }
    float4 o0, o1;
    o0.x = cpy[0]; o0.y = f[0]; o0.z = cpy[1]; o0.w = f[1];
    o1.x = cpy[2]; o1.y = f[2]; o1.z = cpy[3]; o1.w = f[3];
    float* orow = out + ((size_t)bc * 640 + 2 * ri) * 640 + 8 * q;
    *(float4*)(orow)     = o0;
    *(float4*)(orow + 4) = o1;
}

// K4: stage-2 height pass, in-place on out. Writes odd rows r2=2k+1 from the 12
// nonzero taps reading even rows r2-11+2s (wrap pad; 640 even -> parity preserved).
// XCD swizzle: all 12 readers of an even row land in the same XCD's L2.
__global__ __launch_bounds__(256) void k_height2(float* __restrict__ out) {
    int idx = xcd_map(blockIdx.x, gridDim.x) * blockDim.x + threadIdx.x;   // 128*320*160
    int c4 = idx % 160;
    int t1 = idx / 160;
    int k  = t1 % 320;
    int bc = t1 / 320;
    int r2 = 2 * k + 1;
    float* base = out + (size_t)bc * 640 * 640;
    float ax = 0.f, ay = 0.f, az = 0.f, aw = 0.f;
#pragma unroll
    for (int s = 0; s < 12; ++s) {
        int r = r2 - 11 + 2 * s;
        r = r < 0 ? r + 640 : (r >= 640 ? r - 640 : r);
        const float4 v = *(const float4*)(base + r * 640 + 4 * c4);
        const float w = W12[s];
        ax += w * v.x; ay += w * v.y; az += w * v.z; aw += w * v.w;
    }
    float4 o; o.x = ax; o.y = ay; o.z = az; o.w = aw;
    *(float4*)(base + r2 * 640 + 4 * c4) = o;
}

extern "C" void kernel_launch(void* const* d_in, const int* in_sizes, int n_in,
                              void* d_out, int out_size, void* d_ws, size_t ws_size,
                              hipStream_t stream) {
    const float* x = (const float*)d_in[0];
    float* out = (float*)d_out;
    float* mid = (float*)d_ws;  // 128*320*320 floats = 52.4 MB

    // K1: 128*160*40 = 819,200 threads
    k_width1 <<<3200, 256, 0, stream>>>(x, mid);
    // K2: 128*160*80 = 1,638,400 threads (float4)
    k_height1<<<6400, 256, 0, stream>>>(mid);
    // K3: 128*320*80 = 3,276,800 threads
    k_width2 <<<12800, 256, 0, stream>>>(mid, out);
    // K4: 128*320*160 = 6,553,600 threads (float4)
    k_height2<<<25600, 256, 0, stream>>>(out);
}

// Round 6
// 69.066 us; speedup vs baseline: 6.8038x; 2.0540x over previous
//
#include <hip/hip_runtime.h>

typedef float v4f __attribute__((ext_vector_type(4)));

// The 12 nonzero taps of the 23-tap halfband filter (even indices 0,2,..,22).
// The only other nonzero tap is the center (index 11) with weight 1.0 -> pure copy.
__device__ constexpr float W12[12] = {
    -1.20162964e-04f,    1.615524292e-03f, -1.0385513306e-02f,  4.3619155884e-02f,
    -1.45397186478e-01f, 6.1066818237e-01f, 6.1066818237e-01f, -1.45397186478e-01f,
     4.3619155884e-02f, -1.0385513306e-02f, 1.615524292e-03f,  -1.20162964e-04f
};

// Geometry: BC = 128 slices. Stage1: x[160x160] -> mid[320x320] (off=1).
// Stage2: mid[320x320] -> out[640x640] (off=0).
//
// Verified parity semantics (R3/R4):
//  stage1: mid[2m+1][.] = width1(x row m); width1: even col 2i = 12-tap(x[i-6+s]),
//          left pad->0, right pad->x[159]; odd col 2i+1 = x[i] + right-edge corr
//          (i>=154: +sum_{s:i+s>=165} W12[s] * x[159]).
//          mid[2k][.] = sum_s W12[s] * xw[(k-6+s) mod 160]   (xw[m] = width1 row m)
//  stage2: ew[k][.] = width2(mid row k); width2: odd col 2i+1 = 12-tap(mid[i-5+s]),
//          left pad->mid[0], right pad->0; even col 2i = mid[i] + left-edge corr
//          (i<=5: +sum_{s:i+s<=5} W12[s] * mid[0]).
//          out[2k][.] = ew[k][.];  out[2k+1][.] = sum_s W12[s] * ew[(k-5+s) mod 320]

// ---------------- Stage 1 fused: 3200 blocks = 128 bc x 5 row-tiles x 5 col-tiles.
// Tile: mid rows [2*M0, 2*M0+63] x cols [C0, C0+63]. LDS xw: 43 rows (core 32 + halo).
__global__ __launch_bounds__(256) void k_stage1(const float* __restrict__ x,
                                                float* __restrict__ mid) {
    __shared__ float xw[43][64];
    int bid = blockIdx.x;
    int ct = bid % 5, rt = (bid / 5) % 5, bc = bid / 25;
    int M0 = rt * 32;
    int C0 = ct * 64;
    int tid = threadIdx.x;

    // Phase A: xw[e][:] = width1 of x row (M0-6+e mod 160), e = 0..42.
    {
        int g  = tid & 7;              // 8-col group within tile
        int qg = (C0 >> 3) + g;        // global 8-col group in [0,39]
        int i0 = 4 * qg;
        for (int it = 0; it < 2; ++it) {
            int e = it * 32 + (tid >> 3);
            if (e < 43) {
                int m = M0 - 6 + e;
                m = m < 0 ? m + 160 : (m >= 160 ? m - 160 : m);
                const float* xr = x + (bc * 160 + m) * 160;
                float flat[20];
#pragma unroll
                for (int b = 0; b < 5; ++b) {
                    int bq = qg - 2 + b; bq = bq < 0 ? 0 : (bq > 39 ? 39 : bq);
                    *(v4f*)(flat + 4 * b) = *(const v4f*)(xr + 4 * bq);
                }
                float mw[15];
#pragma unroll
                for (int e2 = 0; e2 < 15; ++e2) mw[e2] = flat[e2 + 2];
#pragma unroll
                for (int e2 = 0; e2 < 6; ++e2)  mw[e2] = (i0 - 6 + e2 < 0) ? 0.f : mw[e2];
                float xlast = flat[19];        // = xr[159] whenever g>159 occurs
#pragma unroll
                for (int e2 = 10; e2 < 15; ++e2) mw[e2] = (i0 - 6 + e2 > 159) ? xlast : mw[e2];
                float f[4], cpy[4];
#pragma unroll
                for (int d = 0; d < 4; ++d) {
                    float acc = 0.f;
#pragma unroll
                    for (int s = 0; s < 12; ++s) acc += W12[s] * mw[d + s];
                    f[d] = acc;
                    cpy[d] = mw[d + 6];
                }
                if (i0 >= 151) {               // right-edge copy correction (qg=38,39)
#pragma unroll
                    for (int d = 0; d < 4; ++d) {
                        int i = i0 + d;
                        float c = 0.f;
#pragma unroll
                        for (int s = 0; s < 12; ++s) if (i + s >= 165) c += W12[s];
                        cpy[d] += c * xlast;
                    }
                }
                v4f o0, o1;
                o0.x = f[0]; o0.y = cpy[0]; o0.z = f[1]; o0.w = cpy[1];
                o1.x = f[2]; o1.y = cpy[2]; o1.z = f[3]; o1.w = cpy[3];
                *(v4f*)(&xw[e][8 * g])     = o0;
                *(v4f*)(&xw[e][8 * g + 4]) = o1;
            }
        }
    }
    __syncthreads();

    // Phase B: write mid odd rows (copy) + even rows (12-tap over xw rows).
    {
        int c4   = tid & 15;           // float4 col group
        int slot = tid >> 4;           // 0..15
        float* base = mid + (size_t)bc * 320 * 320;
        for (int it = 0; it < 2; ++it) {
            int kk = it * 16 + slot;   // 0..31
            // odd row 2*(M0+kk)+1 = xw[kk+6]
            v4f oc = *(const v4f*)(&xw[kk + 6][4 * c4]);
            *(v4f*)(base + (size_t)(2 * (M0 + kk) + 1) * 320 + C0 + 4 * c4) = oc;
            // even row 2*(M0+kk) = sum_s W12[s] * xw[kk+s]
            float ax = 0.f, ay = 0.f, az = 0.f, aw = 0.f;
#pragma unroll
            for (int s = 0; s < 12; ++s) {
                const v4f v = *(const v4f*)(&xw[kk + s][4 * c4]);
                const float w = W12[s];
                ax += w * v.x; ay += w * v.y; az += w * v.z; aw += w * v.w;
            }
            v4f oe; oe.x = ax; oe.y = ay; oe.z = az; oe.w = aw;
            *(v4f*)(base + (size_t)(2 * (M0 + kk)) * 320 + C0 + 4 * c4) = oe;
        }
    }
}

// ---------------- Stage 2 fused: 3200 blocks = 128 bc x 5 row-tiles x 5 col-tiles.
// Tile: out rows [2*K0, 2*K0+127] x cols [C0, C0+127]. LDS ew: 75 rows (core 64 + halo).
__global__ __launch_bounds__(256) void k_stage2(const float* __restrict__ mid,
                                                float* __restrict__ out) {
    __shared__ float ew[75][128];
    int bid = blockIdx.x;
    int ct = bid % 5, rt = (bid / 5) % 5, bc = bid / 25;
    int K0 = rt * 64;
    int C0 = ct * 128;
    int tid = threadIdx.x;

    // Phase A: ew[e][:] = width2 of mid row ((K0-5+e) mod 320), e = 0..74.
    {
        int g  = tid & 15;             // 8-col group within tile
        int qg = (C0 >> 3) + g;        // global 8-col group in [0,79]
        int i0 = 4 * qg;
        for (int it = 0; it < 5; ++it) {
            int e = it * 16 + (tid >> 4);
            if (e < 75) {
                int km = K0 - 5 + e;
                km = km < 0 ? km + 320 : (km >= 320 ? km - 320 : km);
                const float* mr = mid + ((size_t)bc * 320 + km) * 320;
                float flat[20];
#pragma unroll
                for (int b = 0; b < 5; ++b) {
                    int bq = qg - 2 + b; bq = bq < 0 ? 0 : (bq > 79 ? 79 : bq);
                    *(v4f*)(flat + 4 * b) = *(const v4f*)(mr + 4 * bq);
                }
                float mw[15];
#pragma unroll
                for (int e2 = 0; e2 < 15; ++e2) mw[e2] = flat[e2 + 3];
                float m0 = flat[0];            // = mr[0] whenever g<0 occurs
#pragma unroll
                for (int e2 = 0; e2 < 5; ++e2)  mw[e2] = (i0 - 5 + e2 < 0) ? m0 : mw[e2];
#pragma unroll
                for (int e2 = 9; e2 < 15; ++e2) mw[e2] = (i0 - 5 + e2 > 319) ? 0.f : mw[e2];
                float f[4], cpy[4];
#pragma unroll
                for (int d = 0; d < 4; ++d) {
                    float acc = 0.f;
#pragma unroll
                    for (int s = 0; s < 12; ++s) acc += W12[s] * mw[d + s];
                    f[d] = acc;
                    cpy[d] = mw[d + 5];
                }
                if (i0 <= 5) {                 // left-edge copy correction (qg=0,1)
#pragma unroll
                    for (int d = 0; d < 4; ++d) {
                        int i = i0 + d;
                        float c = 0.f;
#pragma unroll
                        for (int s = 0; s < 12; ++s) if (i + s <= 5) c += W12[s];
                        cpy[d] += c * m0;
                    }
                }
                v4f o0, o1;
                o0.x = cpy[0]; o0.y = f[0]; o0.z = cpy[1]; o0.w = f[1];
                o1.x = cpy[2]; o1.y = f[2]; o1.z = cpy[3]; o1.w = f[3];
                *(v4f*)(&ew[e][8 * g])     = o0;
                *(v4f*)(&ew[e][8 * g + 4]) = o1;
            }
        }
    }
    __syncthreads();

    // Phase B: write out even rows (copy of ew) + odd rows (12-tap over ew rows).
    {
        int c4   = tid & 31;           // float4 col group
        int slot = tid >> 5;           // 0..7
        float* base = out + (size_t)bc * 640 * 640;
        for (int it = 0; it < 8; ++it) {
            int kk = it * 8 + slot;    // 0..63
            // even row 2*(K0+kk) = ew[kk+5]
            v4f oc = *(const v4f*)(&ew[kk + 5][4 * c4]);
            __builtin_nontemporal_store(oc,
                (v4f*)(base + (size_t)(2 * (K0 + kk)) * 640 + C0 + 4 * c4));
            // odd row 2*(K0+kk)+1 = sum_s W12[s] * ew[kk+s]
            float ax = 0.f, ay = 0.f, az = 0.f, aw = 0.f;
#pragma unroll
            for (int s = 0; s < 12; ++s) {
                const v4f v = *(const v4f*)(&ew[kk + s][4 * c4]);
                const float w = W12[s];
                ax += w * v.x; ay += w * v.y; az += w * v.z; aw += w * v.w;
            }
            v4f oo; oo.x = ax; oo.y = ay; oo.z = az; oo.w = aw;
            __builtin_nontemporal_store(oo,
                (v4f*)(base + (size_t)(2 * (K0 + kk) + 1) * 640 + C0 + 4 * c4));
        }
    }
}

extern "C" void kernel_launch(void* const* d_in, const int* in_sizes, int n_in,
                              void* d_out, int out_size, void* d_ws, size_t ws_size,
                              hipStream_t stream) {
    const float* x = (const float*)d_in[0];
    float* out = (float*)d_out;
    float* mid = (float*)d_ws;  // 128*320*320 floats = 52.4 MB

    k_stage1<<<3200, 256, 0, stream>>>(x, mid);
    k_stage2<<<3200, 256, 0, stream>>>(mid, out);
}

// Round 7
// 50.454 us; speedup vs baseline: 9.3136x; 1.3689x over previous
//
#include <hip/hip_runtime.h>

typedef float v4f __attribute__((ext_vector_type(4)));

// The 12 nonzero taps of the 23-tap halfband filter (even indices 0,2,..,22).
// The only other nonzero tap is the center (index 11) with weight 1.0 -> pure copy.
__device__ constexpr float W12[12] = {
    -1.20162964e-04f,    1.615524292e-03f, -1.0385513306e-02f,  4.3619155884e-02f,
    -1.45397186478e-01f, 6.1066818237e-01f, 6.1066818237e-01f, -1.45397186478e-01f,
     4.3619155884e-02f, -1.0385513306e-02f, 1.615524292e-03f,  -1.20162964e-04f
};

// Bijective XCD-chunking swizzle (grid % 8 == 0).
__device__ __forceinline__ int xcd_map(int bid, int nblk) {
    int cpx = nblk >> 3;
    return (bid & 7) * cpx + (bid >> 3);
}

// Fully fused 4x upsample: x[160x160] -> out[640x640] per slice, one kernel.
// Per block: out tile rows [2K0, 2K0+127] x cols [C0, C0+127], C0 = 2*MC0.
// Verified semantics (R3-R6):
//  width1 (off=1): mid col 2i = 12-tap(x[i-6+s]) [L pad->0, R pad->x[159]];
//                  col 2i+1 = x[i] + R-edge corr (i+s>=165 taps * x[159]).
//  height1: even mid row 2k = sum_s W12[s]*xw[(k-6+s) mod 160]; odd row 2m+1 = xw[m].
//  width2 (off=0): out col 2i = mid[i] + L-edge corr (i+s<=5 taps * mid[0]);
//                  col 2i+1 = 12-tap(mid[i-5+s]) [L pad->mid[0], R pad->0].
//  height2: even out row 2k = ew[k]; odd row 2k+1 = sum_s W12[s]*ew[(k-5+s) mod 320].
// Window bases: XB = K0/2-8 (48 xw rows), mid rows [K0-5,K0+69] (75), cols
// [MC0-8, MC0+71] (80, local col L = global MC0-8+L). All window indices are
// pre-mod; x-row loads wrap mod 160 (width1 is per-row, so wrap commutes).
__global__ __launch_bounds__(256) void k_fused(const float* __restrict__ x,
                                               float* __restrict__ out) {
    __shared__ float xw[48][84];    // width1 rows (x-row resolution), +4 pad
    __shared__ float meb[37][84];   // even mid rows K0-4+2j, j=0..36
    __shared__ float ew[75][132];   // width2 rows (out-col resolution), +4 pad

    int bid = xcd_map(blockIdx.x, gridDim.x);
    int ct = bid % 5, rt = (bid / 5) % 5, bc = bid / 25;
    int K0  = rt * 64;      // mid/ew row tile base
    int MC0 = ct * 64;      // mid col base
    int XB  = K0 / 2 - 8;   // xw row window base (pre-mod, may be negative)
    int tid = threadIdx.x;

    // ---- Phase A: xw[e][:] = width1 of x row (XB+e mod 160), cols MC0-8..MC0+71.
#pragma unroll
    for (int it = 0; it < 2; ++it) {
        int idx = it * 256 + tid;
        int e = idx / 10, g = idx % 10;
        if (e < 48) {
            int m = XB + e;
            m = m < 0 ? m + 160 : (m >= 160 ? m - 160 : m);
            const float* xr = x + (bc * 160 + m) * 160;
            int qg = 8 * ct - 1 + g;       // global 8-col pair group (may be -1 or 40)
            int i0 = 4 * qg;
            float flat[20];
#pragma unroll
            for (int b = 0; b < 5; ++b) {
                int bq = qg - 2 + b; bq = bq < 0 ? 0 : (bq > 39 ? 39 : bq);
                *(v4f*)(flat + 4 * b) = *(const v4f*)(xr + 4 * bq);
            }
            float mw[15];
#pragma unroll
            for (int e2 = 0; e2 < 15; ++e2) mw[e2] = flat[e2 + 2];
#pragma unroll
            for (int e2 = 0; e2 < 6; ++e2)  mw[e2] = (i0 - 6 + e2 < 0) ? 0.f : mw[e2];
            float xlast = flat[19];        // = x[159] whenever right pad occurs
#pragma unroll
            for (int e2 = 10; e2 < 15; ++e2) mw[e2] = (i0 - 6 + e2 > 159) ? xlast : mw[e2];
            float f[4], cpy[4];
#pragma unroll
            for (int d = 0; d < 4; ++d) {
                float acc = 0.f;
#pragma unroll
                for (int s = 0; s < 12; ++s) acc += W12[s] * mw[d + s];
                f[d] = acc;
                cpy[d] = mw[d + 6];
            }
            if (i0 >= 151) {               // stage-1 right-edge copy correction
#pragma unroll
                for (int d = 0; d < 4; ++d) {
                    int i = i0 + d;
                    float c = 0.f;
#pragma unroll
                    for (int s = 0; s < 12; ++s) if (i + s >= 165) c += W12[s];
                    cpy[d] += c * xlast;
                }
            }
            v4f o0, o1;
            o0.x = f[0]; o0.y = cpy[0]; o0.z = f[1]; o0.w = cpy[1];
            o1.x = f[2]; o1.y = cpy[2]; o1.z = f[3]; o1.w = cpy[3];
            *(v4f*)(&xw[e][8 * g])     = o0;
            *(v4f*)(&xw[e][8 * g + 4]) = o1;
        }
    }
    __syncthreads();

    // ---- Phase B: meb[j][:] = even mid row K0-4+2j = sum_s W12[s] * xw[j+s][:].
#pragma unroll
    for (int it = 0; it < 3; ++it) {
        int idx = it * 256 + tid;
        int j = idx / 20, lq = idx % 20;
        if (j < 37) {
            v4f acc = {0.f, 0.f, 0.f, 0.f};
#pragma unroll
            for (int s = 0; s < 12; ++s)
                acc += W12[s] * *(const v4f*)(&xw[j + s][4 * lq]);
            *(v4f*)(&meb[j][4 * lq]) = acc;
        }
    }
    __syncthreads();

    // ---- Phase C: ew[e][:] = width2 of mid row K0-5+e.
    // e even -> mid row odd -> input = xw[e/2+5]; e odd -> input = meb[(e-1)/2].
#pragma unroll
    for (int it = 0; it < 5; ++it) {
        int idx = it * 256 + tid;
        int e = idx / 16, g = idx % 16;
        if (e < 75) {
            const float* row = (e & 1) ? &meb[(e - 1) / 2][0] : &xw[e / 2 + 5][0];
            int i0 = MC0 + 4 * g;
            float flat[20];
#pragma unroll
            for (int b = 0; b < 5; ++b)    // local quads g..g+4; flat[p] = col i0-8+p
                *(v4f*)(flat + 4 * b) = *(const v4f*)(row + 4 * (g + b));
            float mw[15];
#pragma unroll
            for (int e2 = 0; e2 < 15; ++e2) mw[e2] = flat[e2 + 3];
            float m0 = row[8];             // local col 8 = global col MC0 (= mid[0] iff ct==0)
#pragma unroll
            for (int e2 = 0; e2 < 5; ++e2)  mw[e2] = (i0 - 5 + e2 < 0) ? m0 : mw[e2];
#pragma unroll
            for (int e2 = 9; e2 < 15; ++e2) mw[e2] = (i0 - 5 + e2 > 319) ? 0.f : mw[e2];
            float f[4], cpy[4];
#pragma unroll
            for (int d = 0; d < 4; ++d) {
                float acc = 0.f;
#pragma unroll
                for (int s = 0; s < 12; ++s) acc += W12[s] * mw[d + s];
                f[d] = acc;
                cpy[d] = mw[d + 5];
            }
            if (i0 <= 5) {                 // stage-2 left-edge copy correction
#pragma unroll
                for (int d = 0; d < 4; ++d) {
                    int i = i0 + d;
                    float c = 0.f;
#pragma unroll
                    for (int s = 0; s < 12; ++s) if (i + s <= 5) c += W12[s];
                    cpy[d] += c * m0;
                }
            }
            v4f o0, o1;
            o0.x = cpy[0]; o0.y = f[0]; o0.z = cpy[1]; o0.w = f[1];
            o1.x = cpy[2]; o1.y = f[2]; o1.z = cpy[3]; o1.w = f[3];
            *(v4f*)(&ew[e][8 * g])     = o0;
            *(v4f*)(&ew[e][8 * g + 4]) = o1;
        }
    }
    __syncthreads();

    // ---- Phase D: out tile. Sliding 12-row v4f window over ew.
    {
        int c4 = tid & 31, slot = tid >> 5;
        int C0 = MC0 * 2;
        float* base = out + (size_t)bc * 640 * 640 + C0 + 4 * c4;
        v4f w[12];
#pragma unroll
        for (int t = 0; t < 12; ++t) w[t] = *(const v4f*)(&ew[slot * 8 + t][4 * c4]);
#pragma unroll
        for (int u = 0; u < 8; ++u) {
            if (u > 0) {
#pragma unroll
                for (int t = 0; t < 11; ++t) w[t] = w[t + 1];
                w[11] = *(const v4f*)(&ew[slot * 8 + u + 11][4 * c4]);
            }
            int kk = slot * 8 + u;
            // even out row 2(K0+kk) = ew[K0+kk] = w[5]
            __builtin_nontemporal_store(w[5],
                (v4f*)(base + (size_t)(2 * (K0 + kk)) * 640));
            // odd out row = 12-tap over ew rows kk..kk+11
            v4f acc = W12[0] * w[0];
#pragma unroll
            for (int s = 1; s < 12; ++s) acc += W12[s] * w[s];
            __builtin_nontemporal_store(acc,
                (v4f*)(base + (size_t)(2 * (K0 + kk) + 1) * 640));
        }
    }
}

extern "C" void kernel_launch(void* const* d_in, const int* in_sizes, int n_in,
                              void* d_out, int out_size, void* d_ws, size_t ws_size,
                              hipStream_t stream) {
    const float* x = (const float*)d_in[0];
    float* out = (float*)d_out;
    // 3200 blocks = 128 bc x 5 row-tiles x 5 col-tiles (d_ws unused now)
    k_fused<<<3200, 256, 0, stream>>>(x, out);
}

// Round 8
// 49.333 us; speedup vs baseline: 9.5253x; 1.0227x over previous
//
#include <hip/hip_runtime.h>

typedef float v4f __attribute__((ext_vector_type(4)));

// The 12 nonzero taps of the 23-tap halfband filter (even indices 0,2,..,22).
// The only other nonzero tap is the center (index 11) with weight 1.0 -> pure copy.
__device__ constexpr float W12[12] = {
    -1.20162964e-04f,    1.615524292e-03f, -1.0385513306e-02f,  4.3619155884e-02f,
    -1.45397186478e-01f, 6.1066818237e-01f, 6.1066818237e-01f, -1.45397186478e-01f,
     4.3619155884e-02f, -1.0385513306e-02f, 1.615524292e-03f,  -1.20162964e-04f
};

// Bijective XCD-chunking swizzle (grid % 8 == 0).
__device__ __forceinline__ int xcd_map(int bid, int nblk) {
    int cpx = nblk >> 3;
    return (bid & 7) * cpx + (bid >> 3);
}

// Fully fused 4x upsample: x[160x160] -> out[640x640] per slice, one kernel.
// Per block: out tile rows [2K0, 2K0+63] x cols [C0, C0+127], C0 = 2*MC0.
// 64-row tile (vs R7's 128): LDS 40.5 KB -> 4 blocks/CU (was 68 KB -> 2).
// Verified semantics (R3-R7):
//  width1 (off=1): mid col 2i = 12-tap(x[i-6+s]) [L pad->0, R pad->x[159]];
//                  col 2i+1 = x[i] + R-edge corr (i+s>=165 taps * x[159]).
//  height1: even mid row 2k = sum_s W12[s]*xw[(k-6+s) mod 160]; odd row 2m+1 = xw[m].
//  width2 (off=0): out col 2i = mid[i] + L-edge corr (i+s<=5 taps * mid[0]);
//                  col 2i+1 = 12-tap(mid[i-5+s]) [L pad->mid[0], R pad->0].
//  height2: even out row 2k = ew[k]; odd row 2k+1 = sum_s W12[s]*ew[(k-5+s) mod 320].
// Windows: xw rows XB..XB+31 (XB=K0/2-8, mod 160); mid rows [K0-5,K0+37] (43);
// cols [MC0-8, MC0+71] (local col L = global MC0-8+L). Garbage halo cols from
// qg in {-1,40} are either never read or patched (same algebra as R7).
__global__ __launch_bounds__(256) void k_fused(const float* __restrict__ x,
                                               float* __restrict__ out) {
    __shared__ float xw[32][84];    // width1 rows (x-row resolution), +4 pad
    __shared__ float meb[21][84];   // even mid rows K0-4+2j, j=0..20
    __shared__ float ew[43][132];   // width2 rows (out-col resolution), +4 pad

    int bid = xcd_map(blockIdx.x, gridDim.x);
    int ct = bid % 5, rt = (bid / 5) % 10, bc = bid / 50;
    int K0  = rt * 32;      // mid/ew row tile base
    int MC0 = ct * 64;      // mid col base
    int XB  = K0 / 2 - 8;   // xw row window base (pre-mod, may be negative)
    int tid = threadIdx.x;

    // ---- Phase A: xw[e][:] = width1 of x row (XB+e mod 160), cols MC0-8..MC0+71.
#pragma unroll
    for (int it = 0; it < 2; ++it) {
        int idx = it * 256 + tid;
        int e = idx / 10, g = idx % 10;
        if (e < 32) {
            int m = XB + e;
            m = m < 0 ? m + 160 : (m >= 160 ? m - 160 : m);
            const float* xr = x + (bc * 160 + m) * 160;
            int qg = 8 * ct - 1 + g;       // global 8-col pair group (may be -1 or 40)
            int i0 = 4 * qg;
            float flat[20];
#pragma unroll
            for (int b = 0; b < 5; ++b) {
                int bq = qg - 2 + b; bq = bq < 0 ? 0 : (bq > 39 ? 39 : bq);
                *(v4f*)(flat + 4 * b) = *(const v4f*)(xr + 4 * bq);
            }
            float mw[15];
#pragma unroll
            for (int e2 = 0; e2 < 15; ++e2) mw[e2] = flat[e2 + 2];
#pragma unroll
            for (int e2 = 0; e2 < 6; ++e2)  mw[e2] = (i0 - 6 + e2 < 0) ? 0.f : mw[e2];
            float xlast = flat[19];        // = x[159] whenever right pad occurs
#pragma unroll
            for (int e2 = 10; e2 < 15; ++e2) mw[e2] = (i0 - 6 + e2 > 159) ? xlast : mw[e2];
            float f[4], cpy[4];
#pragma unroll
            for (int d = 0; d < 4; ++d) {
                float acc = 0.f;
#pragma unroll
                for (int s = 0; s < 12; ++s) acc += W12[s] * mw[d + s];
                f[d] = acc;
                cpy[d] = mw[d + 6];
            }
            if (i0 >= 151) {               // stage-1 right-edge copy correction
#pragma unroll
                for (int d = 0; d < 4; ++d) {
                    int i = i0 + d;
                    float c = 0.f;
#pragma unroll
                    for (int s = 0; s < 12; ++s) if (i + s >= 165) c += W12[s];
                    cpy[d] += c * xlast;
                }
            }
            v4f o0, o1;
            o0.x = f[0]; o0.y = cpy[0]; o0.z = f[1]; o0.w = cpy[1];
            o1.x = f[2]; o1.y = cpy[2]; o1.z = f[3]; o1.w = cpy[3];
            *(v4f*)(&xw[e][8 * g])     = o0;
            *(v4f*)(&xw[e][8 * g + 4]) = o1;
        }
    }
    __syncthreads();

    // ---- Phase B: meb[j][:] = even mid row K0-4+2j = sum_s W12[s] * xw[j+s][:].
#pragma unroll
    for (int it = 0; it < 2; ++it) {
        int idx = it * 256 + tid;
        int j = idx / 20, lq = idx % 20;
        if (j < 21) {
            v4f acc = {0.f, 0.f, 0.f, 0.f};
#pragma unroll
            for (int s = 0; s < 12; ++s)
                acc += W12[s] * *(const v4f*)(&xw[j + s][4 * lq]);
            *(v4f*)(&meb[j][4 * lq]) = acc;
        }
    }
    __syncthreads();

    // ---- Phase C: ew[e][:] = width2 of mid row K0-5+e.
    // e even -> mid row odd -> input = xw[e/2+5]; e odd -> input = meb[(e-1)/2].
#pragma unroll
    for (int it = 0; it < 3; ++it) {
        int idx = it * 256 + tid;
        int e = idx / 16, g = idx % 16;
        if (e < 43) {
            const float* row = (e & 1) ? &meb[(e - 1) / 2][0] : &xw[e / 2 + 5][0];
            int i0 = MC0 + 4 * g;
            float flat[20];
#pragma unroll
            for (int b = 0; b < 5; ++b)    // local quads g..g+4; flat[p] = col i0-8+p
                *(v4f*)(flat + 4 * b) = *(const v4f*)(row + 4 * (g + b));
            float mw[15];
#pragma unroll
            for (int e2 = 0; e2 < 15; ++e2) mw[e2] = flat[e2 + 3];
            float m0 = row[8];             // local col 8 = global col MC0 (= mid[0] iff ct==0)
#pragma unroll
            for (int e2 = 0; e2 < 5; ++e2)  mw[e2] = (i0 - 5 + e2 < 0) ? m0 : mw[e2];
#pragma unroll
            for (int e2 = 9; e2 < 15; ++e2) mw[e2] = (i0 - 5 + e2 > 319) ? 0.f : mw[e2];
            float f[4], cpy[4];
#pragma unroll
            for (int d = 0; d < 4; ++d) {
                float acc = 0.f;
#pragma unroll
                for (int s = 0; s < 12; ++s) acc += W12[s] * mw[d + s];
                f[d] = acc;
                cpy[d] = mw[d + 5];
            }
            if (i0 <= 5) {                 // stage-2 left-edge copy correction
#pragma unroll
                for (int d = 0; d < 4; ++d) {
                    int i = i0 + d;
                    float c = 0.f;
#pragma unroll
                    for (int s = 0; s < 12; ++s) if (i + s <= 5) c += W12[s];
                    cpy[d] += c * m0;
                }
            }
            v4f o0, o1;
            o0.x = cpy[0]; o0.y = f[0]; o0.z = cpy[1]; o0.w = f[1];
            o1.x = cpy[2]; o1.y = f[2]; o1.z = cpy[3]; o1.w = f[3];
            *(v4f*)(&ew[e][8 * g])     = o0;
            *(v4f*)(&ew[e][8 * g + 4]) = o1;
        }
    }
    __syncthreads();

    // ---- Phase D: out tile. Sliding 12-row v4f window over ew; 4 rows per slot.
    {
        int c4 = tid & 31, slot = tid >> 5;
        int C0 = MC0 * 2;
        float* base = out + (size_t)bc * 640 * 640 + C0 + 4 * c4;
        v4f w[12];
#pragma unroll
        for (int t = 0; t < 12; ++t) w[t] = *(const v4f*)(&ew[slot * 4 + t][4 * c4]);
#pragma unroll
        for (int u = 0; u < 4; ++u) {
            if (u > 0) {
#pragma unroll
                for (int t = 0; t < 11; ++t) w[t] = w[t + 1];
                w[11] = *(const v4f*)(&ew[slot * 4 + u + 11][4 * c4]);
            }
            int kk = slot * 4 + u;
            // even out row 2(K0+kk) = ew[kk+5] = w[5]
            __builtin_nontemporal_store(w[5],
                (v4f*)(base + (size_t)(2 * (K0 + kk)) * 640));
            // odd out row = 12-tap over ew rows kk..kk+11
            v4f acc = W12[0] * w[0];
#pragma unroll
            for (int s = 1; s < 12; ++s) acc += W12[s] * w[s];
            __builtin_nontemporal_store(acc,
                (v4f*)(base + (size_t)(2 * (K0 + kk) + 1) * 640));
        }
    }
}

extern "C" void kernel_launch(void* const* d_in, const int* in_sizes, int n_in,
                              void* d_out, int out_size, void* d_ws, size_t ws_size,
                              hipStream_t stream) {
    const float* x = (const float*)d_in[0];
    float* out = (float*)d_out;
    // 6400 blocks = 128 bc x 10 row-tiles x 5 col-tiles (d_ws unused)
    k_fused<<<6400, 256, 0, stream>>>(x, out);
}

// Round 9
// 46.334 us; speedup vs baseline: 10.1418x; 1.0647x over previous
//
#include <hip/hip_runtime.h>

typedef float v4f __attribute__((ext_vector_type(4)));

// The 12 nonzero taps of the 23-tap halfband filter (even indices 0,2,..,22).
// The only other nonzero tap is the center (index 11) with weight 1.0 -> pure copy.
__device__ constexpr float W12[12] = {
    -1.20162964e-04f,    1.615524292e-03f, -1.0385513306e-02f,  4.3619155884e-02f,
    -1.45397186478e-01f, 6.1066818237e-01f, 6.1066818237e-01f, -1.45397186478e-01f,
     4.3619155884e-02f, -1.0385513306e-02f, 1.615524292e-03f,  -1.20162964e-04f
};

// Bijective XCD-chunking swizzle (grid % 8 == 0).
__device__ __forceinline__ int xcd_map(int bid, int nblk) {
    int cpx = nblk >> 3;
    return (bid & 7) * cpx + (bid >> 3);
}

// Fully fused 4x upsample: x[160x160] -> out[640x640] per slice, one kernel.
// Per block: out tile rows [2K0, 2K0+63] x cols [C0, C0+127], C0 = 2*MC0.
// Semantics verified R3-R8 (absmax 0.0156). Edge patching is provably confined
// to ct==0 (left) / ct==4 (right) blocks -> block-uniform guards.
__global__ __launch_bounds__(256) void k_fused(const float* __restrict__ x,
                                               float* __restrict__ out) {
    __shared__ float xw[32][84];    // width1 rows (x-row resolution), +4 pad
    __shared__ float meb[21][84];   // even mid rows K0-4+2j, j=0..20
    __shared__ float ew[43][132];   // width2 rows (out-col resolution), +4 pad

    int bid = xcd_map(blockIdx.x, gridDim.x);
    int ct = bid % 5, rt = (bid / 5) % 10, bc = bid / 50;
    int K0  = rt * 32;      // mid/ew row tile base
    int MC0 = ct * 64;      // mid col base
    int XB  = K0 / 2 - 8;   // xw row window base (pre-mod, may be negative)
    int tid = threadIdx.x;

    // ---- Phase A: xw[e][:] = width1 of x row (XB+e mod 160), cols MC0-8..MC0+71.
    // filter: f[d] = sum_s W12[s]*flat[d+s+2]; copy col = flat[d+8].
#pragma unroll
    for (int it = 0; it < 2; ++it) {
        int idx = it * 256 + tid;
        int e = idx / 10, g = idx % 10;
        if (e < 32) {
            int m = XB + e;
            m = m < 0 ? m + 160 : (m >= 160 ? m - 160 : m);
            const float* xr = x + (bc * 160 + m) * 160;
            int qg = 8 * ct - 1 + g;       // global 8-col pair group (may be -1 or 40)
            int i0 = 4 * qg;
            float flat[20];
#pragma unroll
            for (int b = 0; b < 5; ++b) {
                int bq = qg - 2 + b; bq = bq < 0 ? 0 : (bq > 39 ? 39 : bq);
                *(v4f*)(flat + 4 * b) = *(const v4f*)(xr + 4 * bq);
            }
            if (ct == 0) {                 // left pad -> 0 (only possible here)
#pragma unroll
                for (int p = 2; p < 8; ++p) flat[p] = (i0 - 8 + p < 0) ? 0.f : flat[p];
            }
            float xlast = flat[19];        // = x[159] whenever right clamp occurred
            if (ct == 4) {                 // right pad -> x[159] (only possible here)
#pragma unroll
                for (int p = 12; p < 17; ++p) flat[p] = (i0 - 8 + p > 159) ? xlast : flat[p];
            }
            float f[4], cpy[4];
#pragma unroll
            for (int d = 0; d < 4; ++d) {
                float acc = 0.f;
#pragma unroll
                for (int s = 0; s < 12; ++s) acc += W12[s] * flat[d + s + 2];
                f[d] = acc;
                cpy[d] = flat[d + 8];
            }
            if (ct == 4 && i0 >= 151) {    // stage-1 right-edge copy correction
#pragma unroll
                for (int d = 0; d < 4; ++d) {
                    int i = i0 + d;
                    float c = 0.f;
#pragma unroll
                    for (int s = 0; s < 12; ++s) if (i + s >= 165) c += W12[s];
                    cpy[d] += c * xlast;
                }
            }
            v4f o0, o1;
            o0.x = f[0]; o0.y = cpy[0]; o0.z = f[1]; o0.w = cpy[1];
            o1.x = f[2]; o1.y = cpy[2]; o1.z = f[3]; o1.w = cpy[3];
            *(v4f*)(&xw[e][8 * g])     = o0;
            *(v4f*)(&xw[e][8 * g + 4]) = o1;
        }
    }
    __syncthreads();

    // ---- Phase B: meb rows in pairs (rows 2p, 2p+1 share 11 of 12 xw reads).
    // 11 pair-slots x 20 quads = 220 items -> single pass.
    {
        int p = tid / 20, lq = tid % 20;
        if (p < 11) {
            int rlast = 2 * p + 12; rlast = rlast < 32 ? rlast : 31;  // p=10: dummy
            v4f r[13];
#pragma unroll
            for (int s = 0; s < 12; ++s) r[s] = *(const v4f*)(&xw[2 * p + s][4 * lq]);
            r[12] = *(const v4f*)(&xw[rlast][4 * lq]);
            v4f a0 = {0.f, 0.f, 0.f, 0.f}, a1 = {0.f, 0.f, 0.f, 0.f};
#pragma unroll
            for (int s = 0; s < 12; ++s) {
                a0 += W12[s] * r[s];
                a1 += W12[s] * r[s + 1];
            }
            *(v4f*)(&meb[2 * p][4 * lq]) = a0;
            if (2 * p + 1 < 21) *(v4f*)(&meb[2 * p + 1][4 * lq]) = a1;
        }
    }
    __syncthreads();

    // ---- Phase C: ew[e][:] = width2 of mid row K0-5+e.
    // e even -> input = xw[e/2+5]; e odd -> input = meb[(e-1)/2].
    // filter: f[d] = sum_s W12[s]*flat[d+s+3]; copy col = flat[d+8].
#pragma unroll
    for (int it = 0; it < 3; ++it) {
        int idx = it * 256 + tid;
        int e = idx / 16, g = idx % 16;
        if (e < 43) {
            const float* row = (e & 1) ? &meb[(e - 1) / 2][0] : &xw[e / 2 + 5][0];
            int i0 = MC0 + 4 * g;
            float flat[20];
#pragma unroll
            for (int b = 0; b < 5; ++b)    // local quads g..g+4; flat[p] = col i0-8+p
                *(v4f*)(flat + 4 * b) = *(const v4f*)(row + 4 * (g + b));
            float f[4], cpy[4];
            if (ct == 0) {                 // left pad -> mid[0] + copy corr (only here)
                float m0 = row[8];         // local col 8 = global mid col 0
#pragma unroll
                for (int p = 3; p < 8; ++p) flat[p] = (i0 - 8 + p < 0) ? m0 : flat[p];
#pragma unroll
                for (int d = 0; d < 4; ++d) {
                    float acc = 0.f;
#pragma unroll
                    for (int s = 0; s < 12; ++s) acc += W12[s] * flat[d + s + 3];
                    f[d] = acc;
                    cpy[d] = flat[d + 8];
                }
                if (i0 <= 5) {
#pragma unroll
                    for (int d = 0; d < 4; ++d) {
                        int i = i0 + d;
                        float c = 0.f;
#pragma unroll
                        for (int s = 0; s < 12; ++s) if (i + s <= 5) c += W12[s];
                        cpy[d] += c * m0;
                    }
                }
            } else {
                if (ct == 4) {             // right pad -> 0 (only here)
#pragma unroll
                    for (int p = 12; p < 18; ++p) flat[p] = (i0 - 8 + p > 319) ? 0.f : flat[p];
                }
#pragma unroll
                for (int d = 0; d < 4; ++d) {
                    float acc = 0.f;
#pragma unroll
                    for (int s = 0; s < 12; ++s) acc += W12[s] * flat[d + s + 3];
                    f[d] = acc;
                    cpy[d] = flat[d + 8];
                }
            }
            v4f o0, o1;
            o0.x = cpy[0]; o0.y = f[0]; o0.z = cpy[1]; o0.w = f[1];
            o1.x = cpy[2]; o1.y = f[2]; o1.z = cpy[3]; o1.w = f[3];
            *(v4f*)(&ew[e][8 * g])     = o0;
            *(v4f*)(&ew[e][8 * g + 4]) = o1;
        }
    }
    __syncthreads();

    // ---- Phase D: out tile. Sliding 12-row v4f window over ew; 4 rows per slot.
    {
        int c4 = tid & 31, slot = tid >> 5;
        int C0 = MC0 * 2;
        float* base = out + (size_t)bc * 640 * 640 + C0 + 4 * c4;
        v4f w[12];
#pragma unroll
        for (int t = 0; t < 12; ++t) w[t] = *(const v4f*)(&ew[slot * 4 + t][4 * c4]);
#pragma unroll
        for (int u = 0; u < 4; ++u) {
            if (u > 0) {
#pragma unroll
                for (int t = 0; t < 11; ++t) w[t] = w[t + 1];
                w[11] = *(const v4f*)(&ew[slot * 4 + u + 11][4 * c4]);
            }
            int kk = slot * 4 + u;
            // even out row 2(K0+kk) = ew[kk+5] = w[5]
            __builtin_nontemporal_store(w[5],
                (v4f*)(base + (size_t)(2 * (K0 + kk)) * 640));
            // odd out row = 12-tap over ew rows kk..kk+11
            v4f acc = W12[0] * w[0];
#pragma unroll
            for (int s = 1; s < 12; ++s) acc += W12[s] * w[s];
            __builtin_nontemporal_store(acc,
                (v4f*)(base + (size_t)(2 * (K0 + kk) + 1) * 640));
        }
    }
}

extern "C" void kernel_launch(void* const* d_in, const int* in_sizes, int n_in,
                              void* d_out, int out_size, void* d_ws, size_t ws_size,
                              hipStream_t stream) {
    const float* x = (const float*)d_in[0];
    float* out = (float*)d_out;
    // 6400 blocks = 128 bc x 10 row-tiles x 5 col-tiles (d_ws unused)
    k_fused<<<6400, 256, 0, stream>>>(x, out);
}